// Round 17
// baseline (61.027 us; speedup 1.0000x reference)
//
#include <hip/hip_runtime.h>
#include <hip/hip_bf16.h>

typedef __attribute__((ext_vector_type(8))) short bf16x8;
typedef __attribute__((ext_vector_type(4))) float f32x4;
typedef __attribute__((ext_vector_type(8))) unsigned short u16x8;

#define KD 2304
#define OUT_PER_B (256 * 1024)
#define CGPL 67600                      // 16*4225: hw-elems per cg plane (x32 ch)

static __device__ __forceinline__ ushort f2bf(float f) {
  union { float f; unsigned int i; } v; v.f = f;
  unsigned int x = v.i;
  x += 0x7fffu + ((x >> 16) & 1u);   // round-to-nearest-even
  return (ushort)(x >> 16);
}

#define GLDS16(gp, lp)                                                         \
  __builtin_amdgcn_global_load_lds(                                            \
      (const __attribute__((address_space(1))) void*)(gp),                     \
      (__attribute__((address_space(3))) void*)(lp), 16, 0, 0)

// swizzle: 16-B chunk g (0..15) of row r -> XOR low 3 bits with r&7 (involution)
#define SWZ(g, r) (((g) & 8) | (((g) ^ (r)) & 7))

#define CVTPK(d, lo, hi) \
  asm("v_cvt_pk_bf16_f32 %0, %1, %2" : "=v"(d) : "v"(lo), "v"(hi))

// ---------------- Kernel 1: fused FIR(v->h) + transpose + weight cast -----------
// xft layout: [cg=8][b=16][hw=4225][32ch]. 8-row bands (1152 blocks, ~4.5/CU);
// register-ring vertical filter, shuffle horizontal filter, double-buffered
// per-wave LDS transpose stage (emit row h-1 while computing row h).
__global__ __launch_bounds__(256) void k_fir5(const float* __restrict__ x,
                                              ushort* __restrict__ xft,
                                              const float* __restrict__ wsrc,
                                              ushort* __restrict__ wb) {
  __shared__ ushort stageAll[4][2][8 * 80];  // per-wave dbuf, 10,240 B total
  const int band = blockIdx.x;               // 0..8; h0 = band*8
  const int cg = blockIdx.y;                 // 0..7
  const int b = blockIdx.z;                  // 0..15
  const int t = threadIdx.x;
  const int wid = t >> 6, lane = t & 63;
  const int c = lane >> 3, o = lane & 7;
  const int cw = cg * 32 + wid * 8;          // wave channel base (global)
  const int h0 = band * 8;
  const int nrows = (band == 8) ? 1 : 8;
  ushort* stg0 = stageAll[wid][0];
  ushort* stg1 = stageAll[wid][1];
  const size_t obase = (size_t)(cg * 16 + b) * 4225;

  // fused weight cast, grid-stride (1152 blocks x 256 thr = 294912)
  {
    int flat = band + 9 * (cg + 8 * b);
    for (int iw = flat * 256 + t; iw < 589824; iw += 294912) {
      float v = wsrc[iw];
      int j = iw % 9;
      int t2 = iw / 9;
      wb[(t2 >> 8) * KD + j * 256 + (t2 & 255)] = f2bf(v);
    }
  }

  const float* xrow = x + ((size_t)(b * 256 + cw + c) << 12) + o * 8;

  float4 rA[8], rB[8];
#define LOADR(s, r)                                                            \
  {                                                                            \
    if ((unsigned)(r) < 64u) {                                                 \
      rA[s] = *(const float4*)(xrow + (r) * 64);                               \
      rB[s] = *(const float4*)(xrow + (r) * 64 + 4);                           \
    } else {                                                                   \
      rA[s] = make_float4(0.f, 0.f, 0.f, 0.f);                                 \
      rB[s] = make_float4(0.f, 0.f, 0.f, 0.f);                                 \
    }                                                                          \
  }

#define EMIT(stg, hrow)                                                        \
  {                                                                            \
    u16x8 pk;                                                                  \
    _Pragma("unroll") for (int cc = 0; cc < 8; ++cc)                           \
        pk[cc] = stg[cc * 80 + (((lane >> 3) ^ cc) << 3) + (lane & 7)];        \
    *(u16x8*)&xft[((obase + (hrow) * 65 + lane) << 5) + wid * 8] = pk;         \
    if (lane == 0) {                                                           \
      u16x8 p2;                                                                \
      _Pragma("unroll") for (int cc = 0; cc < 8; ++cc)                         \
          p2[cc] = stg[cc * 80 + 64];                                          \
      *(u16x8*)&xft[((obase + (hrow) * 65 + 64) << 5) + wid * 8] = p2;         \
    }                                                                          \
  }

  // prologue: rows h0-2 .. h0+2 into slots 6,7,0,1,2  (h0 % 8 == 0)
  LOADR(6, h0 - 2)
  LOADR(7, h0 - 1)
  LOADR(0, h0)
  LOADR(1, h0 + 1)
  LOADR(2, h0 + 2)

#pragma unroll
  for (int hh = 0; hh < 8; ++hh) {
    if (hh < nrows) {
      const int h = h0 + hh;
      LOADR((hh + 3) & 7, h + 3)            // prefetch, ~2 iters of cover

      if (hh > 0) {                          // emit previous row (slack: 1 iter)
        ushort* sp = ((hh - 1) & 1) ? stg1 : stg0;
        EMIT(sp, h - 1)
      }

      const int sm2 = (hh + 6) & 7, sm1 = (hh + 7) & 7;
      const int s00 = hh & 7, sp1 = (hh + 1) & 7;
      float v0 = (rA[sm2].x + rA[sp1].x) + 3.f * (rA[sm1].x + rA[s00].x);
      float v1 = (rA[sm2].y + rA[sp1].y) + 3.f * (rA[sm1].y + rA[s00].y);
      float v2 = (rA[sm2].z + rA[sp1].z) + 3.f * (rA[sm1].z + rA[s00].z);
      float v3 = (rA[sm2].w + rA[sp1].w) + 3.f * (rA[sm1].w + rA[s00].w);
      float v4 = (rB[sm2].x + rB[sp1].x) + 3.f * (rB[sm1].x + rB[s00].x);
      float v5 = (rB[sm2].y + rB[sp1].y) + 3.f * (rB[sm1].y + rB[s00].y);
      float v6 = (rB[sm2].z + rB[sp1].z) + 3.f * (rB[sm1].z + rB[s00].z);
      float v7 = (rB[sm2].w + rB[sp1].w) + 3.f * (rB[sm1].w + rB[s00].w);

      float vm1 = __shfl_up(v7, 1);
      float vm2 = __shfl_up(v6, 1);
      float vp  = __shfl_down(v0, 1);
      if (o == 0) { vm1 = 0.f; vm2 = 0.f; }
      if (o == 7) vp = 0.f;

      const float S = 0.015625f;
      float g0 = ((vm2 + v1) + 3.f * (vm1 + v0)) * S;
      float g1 = ((vm1 + v2) + 3.f * (v0 + v1)) * S;
      float g2 = ((v0 + v3) + 3.f * (v1 + v2)) * S;
      float g3 = ((v1 + v4) + 3.f * (v2 + v3)) * S;
      float g4 = ((v2 + v5) + 3.f * (v3 + v4)) * S;
      float g5 = ((v3 + v6) + 3.f * (v4 + v5)) * S;
      float g6 = ((v4 + v7) + 3.f * (v5 + v6)) * S;
      float g7 = ((v5 + vp) + 3.f * (v6 + v7)) * S;

      unsigned d0, d1, d2, d3;
      CVTPK(d0, g0, g1);
      CVTPK(d1, g2, g3);
      CVTPK(d2, g4, g5);
      CVTPK(d3, g6, g7);
      ushort* sc = (hh & 1) ? stg1 : stg0;
      *(uint4*)&sc[c * 80 + ((o ^ c) << 3)] = make_uint4(d0, d1, d2, d3);
      if (o == 7)
        sc[c * 80 + 64] = f2bf((v6 + 3.f * v7) * S);
      __builtin_amdgcn_wave_barrier();
    }
  }
  {
    ushort* sp = ((nrows - 1) & 1) ? stg1 : stg0;
    EMIT(sp, h0 + nrows - 1)
  }
}

// ---------------- Kernel 2: implicit-conv GEMM, BK=128, plane-B layout ----------
// C[oc=256][n=16384]; BM=128, BN=64, BK=128; 256 thr (4 waves 2m x 2n, 64x32 each)
// B chunk g of slice kt lives in plane cg = (kt&1)*4 + (g>>2), sub (g&3)*8.
__global__ __launch_bounds__(256) void k_gemm3(const ushort* __restrict__ Wb,
                                               const ushort* __restrict__ Xt,
                                               const float* __restrict__ bias,
                                               float* __restrict__ out) {
  __shared__ ushort lA[128 * 128];                 // 32 KB
  __shared__ ushort lB[64 * 128];                  // 16 KB
  const int bid = blockIdx.x;                      // 0..511
  const int work = (bid & 7) * 64 + (bid >> 3);    // XCD-chunked bijective
  const int ntile = work >> 1;
  const int mtile = work & 1;
  const int m0 = mtile * 128;
  const int n0 = ntile * 64;
  const int t = threadIdx.x;
  const int wid = t >> 6, lane = t & 63;
  const int wm = wid >> 1, wn = wid & 1;
  const int lrow = lane & 15, kgrp = lane >> 4;

  const ushort* aB[8];
#pragma unroll
  for (int i = 0; i < 8; ++i) {
    int idx = i * 256 + t;
    int row = idx >> 4, gL = idx & 15;
    aB[i] = Wb + (size_t)(m0 + row) * KD + SWZ(gL, row) * 8;
  }
  const ushort* bB[4];
#pragma unroll
  for (int i = 0; i < 4; ++i) {
    int idx = i * 256 + t;
    int row = idx >> 4, gL = idx & 15;
    int sg = SWZ(gL, row);
    int n = n0 + row;
    int b = n >> 10, oh = (n >> 5) & 31, ow = n & 31;
    bB[i] = Xt +
            (((size_t)((sg >> 2) * 16 + b) * 4225 + (2 * oh) * 65 + 2 * ow) << 5) +
            (sg & 3) * 8;
  }

  f32x4 acc[4][2];
#pragma unroll
  for (int i = 0; i < 4; ++i)
#pragma unroll
    for (int j = 0; j < 2; ++j) acc[i][j] = (f32x4){0.f, 0.f, 0.f, 0.f};

  for (int kt = 0; kt < 18; ++kt) {
    const int j = kt >> 1;
    const int dh = j / 3, dw = j - 3 * dh;
    const int boff = (dh * 65 + dw) * 32 + (kt & 1) * (4 * CGPL * 32);
    const int k0 = kt << 7;
    __syncthreads();
#pragma unroll
    for (int i = 0; i < 8; ++i)
      GLDS16(aB[i] + k0, &lA[(i * 256 + t) * 8]);
#pragma unroll
    for (int i = 0; i < 4; ++i)
      GLDS16(bB[i] + boff, &lB[(i * 256 + t) * 8]);
    __syncthreads();

#pragma unroll
    for (int s = 0; s < 4; ++s) {
      bf16x8 Af[4], Bf[2];
#pragma unroll
      for (int f = 0; f < 4; ++f) {
        int row = wm * 64 + f * 16 + lrow;
        Af[f] = *(const bf16x8*)&lA[row * 128 + SWZ(s * 4 + kgrp, row) * 8];
      }
#pragma unroll
      for (int f = 0; f < 2; ++f) {
        int row = wn * 32 + f * 16 + lrow;
        Bf[f] = *(const bf16x8*)&lB[row * 128 + SWZ(s * 4 + kgrp, row) * 8];
      }
#pragma unroll
      for (int fm = 0; fm < 4; ++fm)
#pragma unroll
        for (int fn = 0; fn < 2; ++fn)
          acc[fm][fn] = __builtin_amdgcn_mfma_f32_16x16x32_bf16(
              Af[fm], Bf[fn], acc[fm][fn], 0, 0, 0);
    }
  }

  f32x4 bv[4];
#pragma unroll
  for (int fm = 0; fm < 4; ++fm)
    bv[fm] = *(const f32x4*)(bias + m0 + wm * 64 + fm * 16 + kgrp * 4);

#pragma unroll
  for (int fm = 0; fm < 4; ++fm) {
#pragma unroll
    for (int fn = 0; fn < 2; ++fn) {
      int nn = n0 + wn * 32 + fn * 16 + lrow;
      int oc = m0 + wm * 64 + fm * 16 + kgrp * 4;
      float* op = out + (size_t)(nn >> 10) * OUT_PER_B + (nn & 1023) +
                  (size_t)oc * 1024;
      op[0]    = acc[fm][fn][0] + bv[fm][0];
      op[1024] = acc[fm][fn][1] + bv[fm][1];
      op[2048] = acc[fm][fn][2] + bv[fm][2];
      op[3072] = acc[fm][fn][3] + bv[fm][3];
    }
  }
}

extern "C" void kernel_launch(void* const* d_in, const int* in_sizes, int n_in,
                              void* d_out, int out_size, void* d_ws, size_t ws_size,
                              hipStream_t stream) {
  const float* x    = (const float*)d_in[0];  // [16,256,64,64]
  const float* w    = (const float*)d_in[1];  // [256,256,3,3]
  const float* bias = (const float*)d_in[2];  // [256]
  float* out = (float*)d_out;                 // [16,256,32,32]

  char* ws = (char*)d_ws;
  ushort* xft = (ushort*)ws;                        // 8*16*4225*32*2 = 34,611,200 B
  ushort* wb  = (ushort*)(ws + 34611200);           // 1,179,648 B

  k_fir5<<<dim3(9, 8, 16), 256, 0, stream>>>(x, xft, w, wb);
  k_gemm3<<<512, 256, 0, stream>>>(wb, xft, bias, out);
}